// Round 1
// baseline (528.225 us; speedup 1.0000x reference)
//
#include <hip/hip_runtime.h>
#include <math.h>

#define NROWS 16384
#define DIN   784
#define DZ    100
#define NS    10

// ws layout (floats):
//  [0..99]     colsum softplus(x@W0.T+b0)   (atomic-accumulated)
//  [100..199]  colsum softplus(x@W1.T+b1)
//  [200]       sum of log(pv_z)             (atomic-accumulated)
//  [201]       Dkl
//  [208..8047] y2[s][i] = y[s][i] * log2(e)   (10 x 784)
//  [8064..9063] z[s][d]                       (10 x 100)
#define WS_Y2 208
#define WS_Z  8064

__device__ __forceinline__ float softplusf(float v) {
    // log(1 + e^v), stable
    return fmaxf(v, 0.f) + log1pf(__expf(-fabsf(v)));
}

// log2(sigmoid(t)) where tp = t * log2(e)  (log2e pre-folded into y2)
__device__ __forceinline__ float l2sig(float tp) {
    return fminf(tp, 0.f) - log2f(1.f + exp2f(-fabsf(tp)));
}

// ---------------- Kernel A: column means of softplus(x@W.T + b) ----------------
// 512 blocks x 256 threads. Block tiles 32 rows x all 200 cols, K-tiled by 16.
__global__ __launch_bounds__(256) void colmean_kernel(
    const float* __restrict__ x,
    const float* __restrict__ W0, const float* __restrict__ b0,
    const float* __restrict__ W1, const float* __restrict__ b1,
    float* __restrict__ ws)
{
    __shared__ float xt[32][20];      // +4 pad keeps float4 alignment, spreads banks
    __shared__ float wt[200 * 16];
    const int tid = threadIdx.x;
    const int tr  = tid & 31;         // row within tile
    const int tj  = tid >> 5;         // 0..7 -> 25 j's each
    const int row0 = blockIdx.x * 32;

    float acc[25];
#pragma unroll
    for (int i = 0; i < 25; ++i) acc[i] = 0.f;

    for (int kt = 0; kt < 49; ++kt) {            // 49 * 16 = 784 exactly
        if (tid < 128) {
            int r = tid >> 2, kq = tid & 3;
            float4 v = *(const float4*)(x + (size_t)(row0 + r) * DIN + kt * 16 + kq * 4);
            *(float4*)(&xt[r][kq * 4]) = v;
        }
        for (int idx = tid; idx < 800; idx += 256) {
            int r = idx >> 2, kq = idx & 3;
            const float* src = (r < 100) ? (W0 + (size_t)r * DIN) : (W1 + (size_t)(r - 100) * DIN);
            float4 v = *(const float4*)(src + kt * 16 + kq * 4);
            *(float4*)(&wt[r * 16 + kq * 4]) = v;
        }
        __syncthreads();
#pragma unroll
        for (int kq = 0; kq < 4; ++kq) {
            float4 xv = *(const float4*)(&xt[tr][kq * 4]);
#pragma unroll
            for (int jj = 0; jj < 25; ++jj) {
                float4 wv = *(const float4*)(&wt[(tj * 25 + jj) * 16 + kq * 4]);
                acc[jj] += xv.x * wv.x + xv.y * wv.y + xv.z * wv.z + xv.w * wv.w;
            }
        }
        __syncthreads();
    }

#pragma unroll
    for (int jj = 0; jj < 25; ++jj) {
        int j = tj * 25 + jj;
        float bias = (j < 100) ? b0[j] : b1[j - 100];
        float v = softplusf(acc[jj] + bias);
        // reduce over the 32 rows (lanes sharing tj live in one 32-lane half)
#pragma unroll
        for (int off = 1; off < 32; off <<= 1) v += __shfl_xor(v, off);
        if (tr == 0) atomicAdd(&ws[j], v);
    }
}

// ---------------- Kernel B1: mean/cov, z, Dkl (single block) ----------------
__global__ __launch_bounds__(256) void middle_kernel(
    const float* __restrict__ eps, float* __restrict__ ws)
{
    __shared__ float red[256];
    const int tid = threadIdx.x;
    float contrib = 0.f;
    if (tid < DZ) {
        const float inv = 1.f / (float)NROWS;
        float mm = ws[tid] * inv;
        float cc = ws[100 + tid] * inv;
        contrib = 0.5f * __logf(cc);
#pragma unroll
        for (int s = 0; s < NS; ++s) {
            float e = eps[s * DZ + tid];
            float zz = mm + cc * e;
            ws[WS_Z + s * DZ + tid] = zz;
            contrib += (0.5f * cc * e * e - 0.5f * zz * zz) * (1.f / NS);
        }
    }
    red[tid] = contrib;
    __syncthreads();
    for (int off = 128; off > 0; off >>= 1) {
        if (tid < off) red[tid] += red[tid + off];
        __syncthreads();
    }
    if (tid == 0) ws[201] = red[0];
}

// ---------------- Kernel B2: y2 = (z @ W2.T + b2) * log2e, wave-per-output ----------------
__global__ __launch_bounds__(256) void y2_kernel(
    const float* __restrict__ W2, const float* __restrict__ b2,
    float* __restrict__ ws)
{
    int wid  = (int)((blockIdx.x * 256 + threadIdx.x) >> 6);
    int lane = threadIdx.x & 63;
    if (wid >= NS * DIN) return;
    int s = wid / DIN, i = wid % DIN;
    const float* zz = ws + WS_Z + s * DZ;
    const float* wr = W2 + (size_t)i * DZ;
    float p = 0.f;
    for (int d = lane; d < DZ; d += 64) p += zz[d] * wr[d];
#pragma unroll
    for (int off = 32; off > 0; off >>= 1) p += __shfl_xor(p, off);
    if (lane == 0) ws[WS_Y2 + wid] = (p + b2[i]) * 1.4426950408889634f;
}

// ---------------- Kernel C: sum over (b,s) of log(prod_i sigmoid((2x-1)*y) + 1e-3) ----------------
// 1024 blocks x 256 threads; one row per wave per iteration (4 rows each).
__global__ __launch_bounds__(256) void pv_kernel(
    const float* __restrict__ x, const float* __restrict__ ws, float* __restrict__ out_sum)
{
    __shared__ float y2[NS * DIN];
    __shared__ float bsum;
    const int tid = threadIdx.x;
    for (int i = tid; i < NS * DIN / 4; i += 256)
        ((float4*)y2)[i] = ((const float4*)(ws + WS_Y2))[i];
    if (tid == 0) bsum = 0.f;
    __syncthreads();

    const int lane = tid & 63;
    const int wid  = (int)((blockIdx.x * 256 + tid) >> 6);
    const int nw   = gridDim.x * 4;
    float wacc = 0.f;

    for (int b = wid; b < NROWS; b += nw) {
        const float4* xr = (const float4*)(x + (size_t)b * DIN);
        float a[NS];
#pragma unroll
        for (int s = 0; s < NS; ++s) a[s] = 0.f;
#pragma unroll
        for (int m = 0; m < 4; ++m) {
            int i4 = lane + m * 64;
            if (i4 < DIN / 4) {
                float4 xv = xr[i4];
                float t0 = 2.f * xv.x - 1.f;
                float t1 = 2.f * xv.y - 1.f;
                float t2 = 2.f * xv.z - 1.f;
                float t3 = 2.f * xv.w - 1.f;
#pragma unroll
                for (int s = 0; s < NS; ++s) {
                    const float4 yv = *(const float4*)(y2 + s * DIN + i4 * 4);
                    a[s] += l2sig(t0 * yv.x) + l2sig(t1 * yv.y)
                          + l2sig(t2 * yv.z) + l2sig(t3 * yv.w);
                }
            }
        }
#pragma unroll
        for (int s = 0; s < NS; ++s) {
#pragma unroll
            for (int off = 32; off > 0; off >>= 1) a[s] += __shfl_xor(a[s], off);
        }
        if (lane == 0) {
            float rs = 0.f;
#pragma unroll
            for (int s = 0; s < NS; ++s) rs += __logf(exp2f(a[s]) + 0.001f);
            wacc += rs;
        }
    }
    if (lane == 0) atomicAdd(&bsum, wacc);
    __syncthreads();
    if (tid == 0) atomicAdd(out_sum, bsum);
}

// ---------------- Kernel D: final scalar ----------------
__global__ void final_kernel(const float* __restrict__ ws, float* __restrict__ out)
{
    float E = ws[200] * (1.f / ((float)NROWS * (float)NS));
    out[0] = -(E + ws[201]);
}

extern "C" void kernel_launch(void* const* d_in, const int* in_sizes, int n_in,
                              void* d_out, int out_size, void* d_ws, size_t ws_size,
                              hipStream_t stream)
{
    const float* x   = (const float*)d_in[0];
    const float* W0  = (const float*)d_in[1];
    const float* b0  = (const float*)d_in[2];
    const float* W1  = (const float*)d_in[3];
    const float* b1  = (const float*)d_in[4];
    const float* W2  = (const float*)d_in[5];
    const float* b2  = (const float*)d_in[6];
    const float* eps = (const float*)d_in[7];
    float* out = (float*)d_out;
    float* ws  = (float*)d_ws;

    hipMemsetAsync(ws, 0, 256 * sizeof(float), stream);
    colmean_kernel<<<512, 256, 0, stream>>>(x, W0, b0, W1, b1, ws);
    middle_kernel<<<1, 256, 0, stream>>>(eps, ws);
    y2_kernel<<<(NS * DIN + 3) / 4, 256, 0, stream>>>(W2, b2, ws);
    pv_kernel<<<1024, 256, 0, stream>>>(x, ws, ws + 200);
    final_kernel<<<1, 1, 0, stream>>>(ws, out);
}

// Round 2
// 149.650 us; speedup vs baseline: 3.5297x; 3.5297x over previous
//
#include <hip/hip_runtime.h>
#include <hip/hip_bf16.h>
#include <math.h>

#define NROWS 16384
#define DIN   784
#define DZ    100
#define NS    10
#define NPAD  208      // 13 * 16 column tiles (200 real + 8 zero)
#define NT    13
#define KTILE 32
#define KTILES 25      // 25*32 = 800 >= 784, tail masked
#define BM    64

typedef unsigned short ushort_t;
typedef short bf16x8 __attribute__((ext_vector_type(8)));
typedef float f32x4  __attribute__((ext_vector_type(4)));

// ws layout (float offsets):
//  [0..199]   colsum softplus (atomic)      [200] pv log-sum (atomic)   [201] Dkl
//  [208..8047]  y2[s][i] = y * log2e        [8064..9063] z[s][d]
//  [16384 ..]   Wb bf16 [208][784]  (81536 floats worth)
#define WS_Y2 208
#define WS_Z  8064
#define WS_WB 16384

__device__ __forceinline__ float softplusf(float v) {
    return fmaxf(v, 0.f) + log1pf(__expf(-fabsf(v)));
}

__device__ __forceinline__ unsigned pack2(float lo, float hi) {
    float2 f2; f2.x = lo; f2.y = hi;
    __hip_bfloat162 h2 = __float22bfloat162_rn(f2);
    return *reinterpret_cast<unsigned*>(&h2);
}

// ---------------- W -> bf16 pre-convert (rows 200..207 zero) ----------------
__global__ __launch_bounds__(256) void wb_kernel(
    const float* __restrict__ W0, const float* __restrict__ W1, ushort_t* __restrict__ Wb)
{
    int e = (blockIdx.x * 256 + threadIdx.x) * 4;
    if (e >= NPAD * DIN) return;
    int row = e / DIN, col = e % DIN;          // DIN % 4 == 0 -> no row crossing
    float4 v = make_float4(0.f, 0.f, 0.f, 0.f);
    if (row < 100)      v = *(const float4*)(W0 + (size_t)row * DIN + col);
    else if (row < 200) v = *(const float4*)(W1 + (size_t)(row - 100) * DIN + col);
    unsigned a = pack2(v.x, v.y), b = pack2(v.z, v.w);
    uint2 o; o.x = a; o.y = b;
    *(uint2*)(Wb + e) = o;
}

// ---------------- MFMA column-sum of softplus(x@W.T + b) ----------------
// 256 blocks x 256 thr (4 waves). BM=64 rows/block, all 208 cols, K-tile 32, dbuf LDS.
__global__ __launch_bounds__(256) void colmean_mfma(
    const float* __restrict__ x, const ushort_t* __restrict__ Wb,
    const float* __restrict__ b0, const float* __restrict__ b1,
    float* __restrict__ ws)
{
    __shared__ ushort_t xt[2][BM * 40];      // stride 40 bf16 = 80B rows (2-way bank alias, free)
    __shared__ ushort_t wt[2][NPAD * 40];
    const int tid  = threadIdx.x;
    const int row0 = blockIdx.x * BM;
    const int xr = tid >> 2, xq = tid & 3;
    const int lane = tid & 63, w = tid >> 6;

    f32x4 acc[NT];
#pragma unroll
    for (int j = 0; j < NT; ++j) acc[j] = (f32x4){0.f, 0.f, 0.f, 0.f};

    float4 xa, xb;
    uint4 wv0, wv1, wv2, wv3;

    auto stage_regs = [&](int kt) {
        int k = kt * KTILE + xq * 8;
        if (k + 8 <= DIN) {
            const float* xp = x + (size_t)(row0 + xr) * DIN + k;
            xa = *(const float4*)(xp);
            xb = *(const float4*)(xp + 4);
        } else {
            xa = make_float4(0.f,0.f,0.f,0.f);
            xb = make_float4(0.f,0.f,0.f,0.f);
        }
        int idx, r, q, kk;
        idx = tid;       r = idx >> 2; q = idx & 3; kk = kt * KTILE + q * 8;
        wv0 = (kk + 8 <= DIN) ? *(const uint4*)(Wb + (size_t)r * DIN + kk) : make_uint4(0,0,0,0);
        idx = tid + 256; r = idx >> 2; q = idx & 3; kk = kt * KTILE + q * 8;
        wv1 = (kk + 8 <= DIN) ? *(const uint4*)(Wb + (size_t)r * DIN + kk) : make_uint4(0,0,0,0);
        idx = tid + 512; r = idx >> 2; q = idx & 3; kk = kt * KTILE + q * 8;
        wv2 = (kk + 8 <= DIN) ? *(const uint4*)(Wb + (size_t)r * DIN + kk) : make_uint4(0,0,0,0);
        if (tid < 64) {
            idx = tid + 768; r = idx >> 2; q = idx & 3; kk = kt * KTILE + q * 8;
            wv3 = (kk + 8 <= DIN) ? *(const uint4*)(Wb + (size_t)r * DIN + kk) : make_uint4(0,0,0,0);
        }
    };

    auto cvt_store = [&](int buf) {
        uint4 xp;
        xp.x = pack2(xa.x, xa.y); xp.y = pack2(xa.z, xa.w);
        xp.z = pack2(xb.x, xb.y); xp.w = pack2(xb.z, xb.w);
        *(uint4*)(&xt[buf][xr * 40 + xq * 8]) = xp;
        int idx;
        idx = tid;       *(uint4*)(&wt[buf][(idx >> 2) * 40 + (idx & 3) * 8]) = wv0;
        idx = tid + 256; *(uint4*)(&wt[buf][(idx >> 2) * 40 + (idx & 3) * 8]) = wv1;
        idx = tid + 512; *(uint4*)(&wt[buf][(idx >> 2) * 40 + (idx & 3) * 8]) = wv2;
        if (tid < 64) { idx = tid + 768; *(uint4*)(&wt[buf][(idx >> 2) * 40 + (idx & 3) * 8]) = wv3; }
    };

    auto compute = [&](int buf) {
        const int abase = (w * 16 + (lane & 15)) * 40 + (lane >> 4) * 8;
        bf16x8 af = *(const bf16x8*)(&xt[buf][abase]);
        const int bbase = (lane & 15) * 40 + (lane >> 4) * 8;
#pragma unroll
        for (int jt = 0; jt < NT; ++jt) {
            bf16x8 bfr = *(const bf16x8*)(&wt[buf][bbase + jt * 16 * 40]);
            acc[jt] = __builtin_amdgcn_mfma_f32_16x16x32_bf16(af, bfr, acc[jt], 0, 0, 0);
        }
    };

    stage_regs(0);
    cvt_store(0);
    __syncthreads();
    for (int kt = 0; kt < KTILES; ++kt) {
        int cur = kt & 1;
        if (kt + 1 < KTILES) stage_regs(kt + 1);   // issue next-tile global loads
        compute(cur);                              // ds_read + mfma on current
        if (kt + 1 < KTILES) cvt_store(cur ^ 1);   // waits loads, fills other buf
        __syncthreads();
    }

    // epilogue: softplus+bias, reduce 16 rows per wave, atomic per column
    const int jcol = lane & 15, rgrp = lane >> 4;
#pragma unroll
    for (int jt = 0; jt < NT; ++jt) {
        int j = jt * 16 + jcol;
        float bias = (j < 100) ? b0[j] : ((j < 200) ? b1[j - 100] : 0.f);
        float v = 0.f;
#pragma unroll
        for (int r = 0; r < 4; ++r) v += softplusf(acc[jt][r] + bias);
        v += __shfl_xor(v, 16);
        v += __shfl_xor(v, 32);
        if (j < 200 && rgrp == 0) atomicAdd(&ws[j], v);
    }
}

// ---------------- mean/cov, z, Dkl (single block) ----------------
__global__ __launch_bounds__(256) void middle_kernel(
    const float* __restrict__ eps, float* __restrict__ ws)
{
    __shared__ float red[256];
    const int tid = threadIdx.x;
    float contrib = 0.f;
    if (tid < DZ) {
        const float inv = 1.f / (float)NROWS;
        float mm = ws[tid] * inv;
        float cc = ws[100 + tid] * inv;
        contrib = 0.5f * __logf(cc);
#pragma unroll
        for (int s = 0; s < NS; ++s) {
            float e = eps[s * DZ + tid];
            float zz = mm + cc * e;
            ws[WS_Z + s * DZ + tid] = zz;
            contrib += (0.5f * cc * e * e - 0.5f * zz * zz) * (1.f / NS);
        }
    }
    red[tid] = contrib;
    __syncthreads();
    for (int off = 128; off > 0; off >>= 1) {
        if (tid < off) red[tid] += red[tid + off];
        __syncthreads();
    }
    if (tid == 0) ws[201] = red[0];
}

// ---------------- y2 = (z @ W2.T + b2) * log2e ----------------
__global__ __launch_bounds__(256) void y2_kernel(
    const float* __restrict__ W2, const float* __restrict__ b2,
    float* __restrict__ ws)
{
    int wid  = (int)((blockIdx.x * 256 + threadIdx.x) >> 6);
    int lane = threadIdx.x & 63;
    if (wid >= NS * DIN) return;
    int s = wid / DIN, i = wid % DIN;
    const float* zz = ws + WS_Z + s * DZ;
    const float* wr = W2 + (size_t)i * DZ;
    float p = 0.f;
    for (int d = lane; d < DZ; d += 64) p += zz[d] * wr[d];
#pragma unroll
    for (int off = 32; off > 0; off >>= 1) p += __shfl_xor(p, off);
    if (lane == 0) ws[WS_Y2 + wid] = (p + b2[i]) * 1.4426950408889634f;
}

// ---------------- sum over (b,s) of log(prod_i sigmoid((2x-1)*y) + 1e-3) ----------------
__global__ __launch_bounds__(256) void pv_kernel(
    const float* __restrict__ x, const float* __restrict__ ws, float* __restrict__ out_sum)
{
    __shared__ float y2[NS * DIN];
    __shared__ float bsum;
    const int tid = threadIdx.x;
    for (int i = tid; i < NS * DIN / 4; i += 256)
        ((float4*)y2)[i] = ((const float4*)(ws + WS_Y2))[i];
    if (tid == 0) bsum = 0.f;
    __syncthreads();

    const int lane = tid & 63;
    const int wid  = (int)((blockIdx.x * 256 + tid) >> 6);
    const int nw   = gridDim.x * 4;
    float wacc = 0.f;

    for (int b = wid; b < NROWS; b += nw) {
        const float4* xr = (const float4*)(x + (size_t)b * DIN);
        float a[NS];
#pragma unroll
        for (int s = 0; s < NS; ++s) a[s] = 0.f;
#pragma unroll
        for (int m = 0; m < 4; ++m) {
            int i4 = lane + m * 64;
            if (i4 < DIN / 4) {
                float4 xv = xr[i4];
                float n0 = 1.f - 2.f * xv.x;    // negated arg folds sign into the mul
                float n1 = 1.f - 2.f * xv.y;
                float n2 = 1.f - 2.f * xv.z;
                float n3 = 1.f - 2.f * xv.w;
#pragma unroll
                for (int s = 0; s < NS; ++s) {
                    const float4 yv = *(const float4*)(y2 + s * DIN + i4 * 4);
                    // log2(sigmoid(t)) = -log2(1 + 2^(-t2))  with t2 = t*log2e pre-folded in y2
                    a[s] -= __builtin_amdgcn_logf(1.f + __builtin_amdgcn_exp2f(n0 * yv.x));
                    a[s] -= __builtin_amdgcn_logf(1.f + __builtin_amdgcn_exp2f(n1 * yv.y));
                    a[s] -= __builtin_amdgcn_logf(1.f + __builtin_amdgcn_exp2f(n2 * yv.z));
                    a[s] -= __builtin_amdgcn_logf(1.f + __builtin_amdgcn_exp2f(n3 * yv.w));
                }
            }
        }
#pragma unroll
        for (int s = 0; s < NS; ++s) {
#pragma unroll
            for (int off = 32; off > 0; off >>= 1) a[s] += __shfl_xor(a[s], off);
        }
        if (lane == 0) {
            float rs = 0.f;
#pragma unroll
            for (int s = 0; s < NS; ++s) rs += __logf(__builtin_amdgcn_exp2f(a[s]) + 0.001f);
            wacc += rs;
        }
    }
    if (lane == 0) atomicAdd(&bsum, wacc);
    __syncthreads();
    if (tid == 0) atomicAdd(out_sum, bsum);
}

// ---------------- final scalar ----------------
__global__ void final_kernel(const float* __restrict__ ws, float* __restrict__ out)
{
    float E = ws[200] * (1.f / ((float)NROWS * (float)NS));
    out[0] = -(E + ws[201]);
}

extern "C" void kernel_launch(void* const* d_in, const int* in_sizes, int n_in,
                              void* d_out, int out_size, void* d_ws, size_t ws_size,
                              hipStream_t stream)
{
    const float* x   = (const float*)d_in[0];
    const float* W0  = (const float*)d_in[1];
    const float* b0  = (const float*)d_in[2];
    const float* W1  = (const float*)d_in[3];
    const float* b1  = (const float*)d_in[4];
    const float* W2  = (const float*)d_in[5];
    const float* b2  = (const float*)d_in[6];
    const float* eps = (const float*)d_in[7];
    float* out = (float*)d_out;
    float* ws  = (float*)d_ws;
    ushort_t* Wb = (ushort_t*)(ws + WS_WB);

    hipMemsetAsync(ws, 0, 256 * sizeof(float), stream);
    wb_kernel<<<(NPAD * DIN / 4 + 255) / 256, 256, 0, stream>>>(W0, W1, Wb);
    colmean_mfma<<<NROWS / BM, 256, 0, stream>>>(x, Wb, b0, b1, ws);
    middle_kernel<<<1, 256, 0, stream>>>(eps, ws);
    y2_kernel<<<(NS * DIN * 64) / 256, 256, 0, stream>>>(W2, b2, ws);
    pv_kernel<<<1024, 256, 0, stream>>>(x, ws, ws + 200);
    final_kernel<<<1, 1, 0, stream>>>(ws, out);
}

// Round 3
// 120.841 us; speedup vs baseline: 4.3712x; 1.2384x over previous
//
#include <hip/hip_runtime.h>
#include <hip/hip_bf16.h>
#include <math.h>

#define NROWS 16384
#define DIN   784
#define DZ    100
#define NS    10
#define NCT   16           // 16 col-tiles x 16 = 256 cols (200 real + 56 zero pad)
#define KTILES 25          // 25 * 32 = 800 >= 784
#define BM    32

typedef unsigned short ushort_t;
typedef short bf16x8 __attribute__((ext_vector_type(8)));
typedef float f32x4  __attribute__((ext_vector_type(4)));

// ws layout (float offsets):
//  [0..199]   colsum softplus (atomic)   [200] pv log-sum (atomic)   [201] Dkl
//  [208..8047] y2[s][i] = y * log2e      [8064..9063] z[s][d]
//  [16384..]   Wb2: bf16 fragment-swizzled W, 25*16*512 ushorts (400 KB)
#define WS_Y2 208
#define WS_Z  8064
#define WS_WB 16384

__device__ __forceinline__ float softplusf(float v) {
    return fmaxf(v, 0.f) + log1pf(__expf(-fabsf(v)));
}
__device__ __forceinline__ unsigned pack2(float lo, float hi) {
    float2 f2; f2.x = lo; f2.y = hi;
    __hip_bfloat162 h2 = __float22bfloat162_rn(f2);
    return *reinterpret_cast<unsigned*>(&h2);
}

// ---- W -> bf16, pre-swizzled to MFMA B-fragment order ----
// Wb2[((kt*16 + ct)*64 + lane)*8 + j] = W[ct*16 + (lane&15)][kt*32 + (lane>>4)*8 + j]
__global__ __launch_bounds__(256) void wb2_kernel(
    const float* __restrict__ W0, const float* __restrict__ W1, ushort_t* __restrict__ Wb)
{
    int t = blockIdx.x * 256 + threadIdx.x;
    if (t >= KTILES * NCT * 64) return;
    int kt = t >> 10;
    int r  = t & 1023;
    int ct = r >> 6, l = r & 63;
    int col = ct * 16 + (l & 15);
    int k0  = kt * 32 + (l >> 4) * 8;
    uint4 o = make_uint4(0u, 0u, 0u, 0u);
    if (col < 200 && k0 < DIN) {           // k0 multiple of 8, DIN%8==0 -> frag fully valid
        const float* src = (col < 100 ? W0 + (size_t)col * DIN
                                      : W1 + (size_t)(col - 100) * DIN) + k0;
        float4 a = *(const float4*)src;
        float4 b = *(const float4*)(src + 4);
        o.x = pack2(a.x, a.y); o.y = pack2(a.z, a.w);
        o.z = pack2(b.x, b.y); o.w = pack2(b.z, b.w);
    }
    *(uint4*)(Wb + (size_t)t * 8) = o;
}

// ---- MFMA column-sum of softplus(x@W.T + b) ----
// 512 blocks x 512 thr (8 waves). BM=32 rows: rt = w&1 picks 16 rows, g = w>>1 picks 4 col-tiles.
// W double-buffered in LDS via global_load_lds; x A-frags straight from global, reg-dbuf.
__global__ __launch_bounds__(512) void colmean_mfma(
    const float* __restrict__ x, const ushort_t* __restrict__ Wb,
    const float* __restrict__ b0, const float* __restrict__ b1,
    float* __restrict__ ws)
{
    __shared__ ushort_t wt[2][NCT * 512];
    const int tid  = threadIdx.x;
    const int lane = tid & 63, w = tid >> 6;
    const int rt = w & 1, g = w >> 1;
    const int row = blockIdx.x * BM + rt * 16 + (lane & 15);
    const int klane = (lane >> 4) * 8;
    const float* xrow = x + (size_t)row * DIN + klane;

    f32x4 acc[4];
#pragma unroll
    for (int jj = 0; jj < 4; ++jj) acc[jj] = (f32x4){0.f, 0.f, 0.f, 0.f};

    auto xload = [&](int kt, float4& a, float4& b) {
        int k = kt * 32 + klane;
        if (k + 8 <= DIN) {
            a = *(const float4*)(xrow + kt * 32);
            b = *(const float4*)(xrow + kt * 32 + 4);
        } else {
            a = make_float4(0.f, 0.f, 0.f, 0.f);
            b = make_float4(0.f, 0.f, 0.f, 0.f);
        }
    };
    auto wstage = [&](int kt, int buf) {
        // wave w stages col-tiles 2w and 2w+1 (1 KB each) via async global->LDS
        const ushort_t* src0 = Wb + (size_t)(kt * NCT + 2 * w) * 512 + lane * 8;
        __builtin_amdgcn_global_load_lds(
            (const __attribute__((address_space(1))) unsigned*)(src0),
            (__attribute__((address_space(3))) unsigned*)(&wt[buf][(2 * w) * 512]),
            16, 0, 0);
        __builtin_amdgcn_global_load_lds(
            (const __attribute__((address_space(1))) unsigned*)(src0 + 512),
            (__attribute__((address_space(3))) unsigned*)(&wt[buf][(2 * w + 1) * 512]),
            16, 0, 0);
    };

    float4 xa0, xa1, xb0, xb1;
    xload(0, xa0, xa1);
    wstage(0, 0);
    __syncthreads();

    for (int kt = 0; kt < KTILES; ++kt) {
        const int cur = kt & 1;
        if (kt + 1 < KTILES) {
            xload(kt + 1, xb0, xb1);       // async into regs
            wstage(kt + 1, cur ^ 1);       // async into other LDS buf
        }
        bf16x8 af;
        unsigned* afp = (unsigned*)&af;
        afp[0] = pack2(xa0.x, xa0.y); afp[1] = pack2(xa0.z, xa0.w);
        afp[2] = pack2(xa1.x, xa1.y); afp[3] = pack2(xa1.z, xa1.w);
#pragma unroll
        for (int jj = 0; jj < 4; ++jj) {
            bf16x8 bf = *(const bf16x8*)(&wt[cur][(g * 4 + jj) * 512 + lane * 8]);
            acc[jj] = __builtin_amdgcn_mfma_f32_16x16x32_bf16(af, bf, acc[jj], 0, 0, 0);
        }
        xa0 = xb0; xa1 = xb1;
        __syncthreads();                   // drains glds vmcnt + releases buffers
    }

    // epilogue: softplus+bias, sum the wave's 16 rows, one atomic per column
    const int jcol = lane & 15, rgrp = lane >> 4;
#pragma unroll
    for (int jj = 0; jj < 4; ++jj) {
        int j = (g * 4 + jj) * 16 + jcol;
        float bias = (j < 100) ? b0[j] : ((j < 200) ? b1[j - 100] : 0.f);
        float v = 0.f;
#pragma unroll
        for (int r = 0; r < 4; ++r) v += softplusf(acc[jj][r] + bias);
        v += __shfl_xor(v, 16);
        v += __shfl_xor(v, 32);
        if (j < 200 && rgrp == 0) atomicAdd(&ws[j], v);
    }
}

// ---- mean/cov, z, Dkl (single block) ----
__global__ __launch_bounds__(256) void middle_kernel(
    const float* __restrict__ eps, float* __restrict__ ws)
{
    __shared__ float red[256];
    const int tid = threadIdx.x;
    float contrib = 0.f;
    if (tid < DZ) {
        const float inv = 1.f / (float)NROWS;
        float mm = ws[tid] * inv;
        float cc = ws[100 + tid] * inv;
        contrib = 0.5f * __logf(cc);
#pragma unroll
        for (int s = 0; s < NS; ++s) {
            float e = eps[s * DZ + tid];
            float zz = mm + cc * e;
            ws[WS_Z + s * DZ + tid] = zz;
            contrib += (0.5f * cc * e * e - 0.5f * zz * zz) * (1.f / NS);
        }
    }
    red[tid] = contrib;
    __syncthreads();
    for (int off = 128; off > 0; off >>= 1) {
        if (tid < off) red[tid] += red[tid + off];
        __syncthreads();
    }
    if (tid == 0) ws[201] = red[0];
}

// ---- y2 = (z @ W2.T + b2) * log2e ----
__global__ __launch_bounds__(256) void y2_kernel(
    const float* __restrict__ W2, const float* __restrict__ b2,
    float* __restrict__ ws)
{
    int wid  = (int)((blockIdx.x * 256 + threadIdx.x) >> 6);
    int lane = threadIdx.x & 63;
    if (wid >= NS * DIN) return;
    int s = wid / DIN, i = wid % DIN;
    const float* zz = ws + WS_Z + s * DZ;
    const float* wr = W2 + (size_t)i * DZ;
    float p = 0.f;
    for (int d = lane; d < DZ; d += 64) p += zz[d] * wr[d];
#pragma unroll
    for (int off = 32; off > 0; off >>= 1) p += __shfl_xor(p, off);
    if (lane == 0) ws[WS_Y2 + wid] = (p + b2[i]) * 1.4426950408889634f;
}

// ---- sum over (b,s) of log(prod_i sigmoid((2x-1)*y) + 1e-3), log2 domain ----
__global__ __launch_bounds__(256) void pv_kernel(
    const float* __restrict__ x, const float* __restrict__ ws, float* __restrict__ out_sum)
{
    __shared__ float y2[NS * DIN];
    __shared__ float bsum;
    const int tid = threadIdx.x;
    for (int i = tid; i < NS * DIN / 4; i += 256)
        ((float4*)y2)[i] = ((const float4*)(ws + WS_Y2))[i];
    if (tid == 0) bsum = 0.f;
    __syncthreads();

    const int lane = tid & 63;
    const int wid  = (int)((blockIdx.x * 256 + tid) >> 6);
    const int nw   = gridDim.x * 4;
    float wacc = 0.f;

    for (int b = wid; b < NROWS; b += nw) {
        const float4* xr = (const float4*)(x + (size_t)b * DIN);
        float a[NS];
#pragma unroll
        for (int s = 0; s < NS; ++s) a[s] = 0.f;
#pragma unroll
        for (int m = 0; m < 4; ++m) {
            int i4 = lane + m * 64;
            if (i4 < DIN / 4) {
                float4 xv = xr[i4];
                float n0 = 1.f - 2.f * xv.x;
                float n1 = 1.f - 2.f * xv.y;
                float n2 = 1.f - 2.f * xv.z;
                float n3 = 1.f - 2.f * xv.w;
#pragma unroll
                for (int s = 0; s < NS; ++s) {
                    const float4 yv = *(const float4*)(y2 + s * DIN + i4 * 4);
                    // a -= log2(1 + 2^(-t*log2e-ish)): y2 pre-scaled, v_log_f32 is log2
                    a[s] -= __builtin_amdgcn_logf(1.f + __builtin_amdgcn_exp2f(n0 * yv.x));
                    a[s] -= __builtin_amdgcn_logf(1.f + __builtin_amdgcn_exp2f(n1 * yv.y));
                    a[s] -= __builtin_amdgcn_logf(1.f + __builtin_amdgcn_exp2f(n2 * yv.z));
                    a[s] -= __builtin_amdgcn_logf(1.f + __builtin_amdgcn_exp2f(n3 * yv.w));
                }
            }
        }
#pragma unroll
        for (int s = 0; s < NS; ++s) {
#pragma unroll
            for (int off = 32; off > 0; off >>= 1) a[s] += __shfl_xor(a[s], off);
        }
        if (lane == 0) {
            float rs = 0.f;
#pragma unroll
            for (int s = 0; s < NS; ++s) rs += __logf(__builtin_amdgcn_exp2f(a[s]) + 0.001f);
            wacc += rs;
        }
    }
    if (lane == 0) atomicAdd(&bsum, wacc);
    __syncthreads();
    if (tid == 0) atomicAdd(out_sum, bsum);
}

// ---- final scalar ----
__global__ void final_kernel(const float* __restrict__ ws, float* __restrict__ out)
{
    float E = ws[200] * (1.f / ((float)NROWS * (float)NS));
    out[0] = -(E + ws[201]);
}

extern "C" void kernel_launch(void* const* d_in, const int* in_sizes, int n_in,
                              void* d_out, int out_size, void* d_ws, size_t ws_size,
                              hipStream_t stream)
{
    const float* x   = (const float*)d_in[0];
    const float* W0  = (const float*)d_in[1];
    const float* b0  = (const float*)d_in[2];
    const float* W1  = (const float*)d_in[3];
    const float* b1  = (const float*)d_in[4];
    const float* W2  = (const float*)d_in[5];
    const float* b2  = (const float*)d_in[6];
    const float* eps = (const float*)d_in[7];
    float* out = (float*)d_out;
    float* ws  = (float*)d_ws;
    ushort_t* Wb = (ushort_t*)(ws + WS_WB);

    hipMemsetAsync(ws, 0, 256 * sizeof(float), stream);
    wb2_kernel<<<(KTILES * NCT * 64 + 255) / 256, 256, 0, stream>>>(W0, W1, Wb);
    colmean_mfma<<<NROWS / BM, 512, 0, stream>>>(x, Wb, b0, b1, ws);
    middle_kernel<<<1, 256, 0, stream>>>(eps, ws);
    y2_kernel<<<(NS * DIN * 64) / 256, 256, 0, stream>>>(W2, b2, ws);
    pv_kernel<<<1024, 256, 0, stream>>>(x, ws, ws + 200);
    final_kernel<<<1, 1, 0, stream>>>(ws, out);
}

// Round 4
// 103.433 us; speedup vs baseline: 5.1069x; 1.1683x over previous
//
#include <hip/hip_runtime.h>
#include <hip/hip_bf16.h>
#include <math.h>

#define NROWS 16384
#define DIN   784
#define DZ    100
#define NS    10
#define NCT   16           // 16 col-tiles x 16 = 256 cols (200 real + 56 zero pad)
#define KTILES 25          // 25 * 32 = 800 >= 784, tail frags zeroed
#define BM    32
#define STRIPS 512         // NROWS / BM

typedef unsigned short ushort_t;
typedef short bf16x8 __attribute__((ext_vector_type(8)));
typedef float f32x4  __attribute__((ext_vector_type(4)));

// ws layout (float offsets):
//  [0..199]   colsum softplus (atomic)   [200] pv log-sum (atomic)   [201] Dkl
//  [208..8047] y2[s][i] = y * log2e      [8064..9063] z[s][d]
//  [16384..]   Wb2: bf16 fragment-swizzled W, 25*16*512 ushorts (400 KB)
#define WS_Y2 208
#define WS_Z  8064
#define WS_WB 16384

__device__ __forceinline__ float softplusf(float v) {
    return fmaxf(v, 0.f) + log1pf(__expf(-fabsf(v)));
}
__device__ __forceinline__ unsigned pack2(float lo, float hi) {
    float2 f2; f2.x = lo; f2.y = hi;
    __hip_bfloat162 h2 = __float22bfloat162_rn(f2);
    return *reinterpret_cast<unsigned*>(&h2);
}

// ---- W -> bf16, pre-swizzled to MFMA B-fragment order ----
// Wb2[((kt*16 + ct)*64 + lane)*8 + j] = W[ct*16 + (lane&15)][kt*32 + (lane>>4)*8 + j]
__global__ __launch_bounds__(256) void wb2_kernel(
    const float* __restrict__ W0, const float* __restrict__ W1, ushort_t* __restrict__ Wb)
{
    int t = blockIdx.x * 256 + threadIdx.x;
    if (t >= KTILES * NCT * 64) return;
    int kt = t >> 10;
    int r  = t & 1023;
    int ct = r >> 6, l = r & 63;
    int col = ct * 16 + (l & 15);
    int k0  = kt * 32 + (l >> 4) * 8;
    uint4 o = make_uint4(0u, 0u, 0u, 0u);
    if (col < 200 && k0 < DIN) {           // frag-aligned tail: k0=784,792 zeroed
        const float* src = (col < 100 ? W0 + (size_t)col * DIN
                                      : W1 + (size_t)(col - 100) * DIN) + k0;
        float4 a = *(const float4*)src;
        float4 b = *(const float4*)(src + 4);
        o.x = pack2(a.x, a.y); o.y = pack2(a.z, a.w);
        o.z = pack2(b.x, b.y); o.w = pack2(b.z, b.w);
    }
    *(uint4*)(Wb + (size_t)t * 8) = o;
}

// ---- MFMA column-sum of softplus(x@W.T + b) ----
// grid 1024 = 512 strips x 2 col-halves, 256 thr (4 waves): rt=w&1 row half, g=w>>1 col quarter.
// x staged to LDS via glds with pi-swizzled global source (pi(row,c)=row*8+((c+row)&7))
// so ds_read_b128 of A-frags is bank-conflict-free while LDS dest stays glds-linear.
__global__ __launch_bounds__(256) void colmean_mfma(
    const float* __restrict__ x, const ushort_t* __restrict__ Wb,
    const float* __restrict__ b0, const float* __restrict__ b1,
    float* __restrict__ ws)
{
    __shared__ ushort_t wt[2][8 * 512];    // 8 tiles x 1KB per buf
    __shared__ float    xl[2][1024];       // 32 rows x 8 chunks x 16B per buf
    const int tid = threadIdx.x;
    const int lane = tid & 63, w = tid >> 6;
    const int rt = w & 1, g = w >> 1;

    // XCD-chunked swizzle: each XCD gets 128 consecutive swz = 64 strips x both halves
    int b = blockIdx.x;
    int swz = (b & 7) * 128 + (b >> 3);
    const int strip = swz >> 1, ch = swz & 1;
    const int row0 = strip * BM;

    // x glds lane mapping: slot s = w*64+lane holds (row=s>>3, chunk c=((s&7)-row)&7)
    const int sslot = w * 64 + lane;
    const int srow  = sslot >> 3;
    const int sc    = ((sslot & 7) - srow) & 7;
    const float* xrowp = x + (size_t)(row0 + srow) * DIN;

    f32x4 acc[4];
#pragma unroll
    for (int jj = 0; jj < 4; ++jj) acc[jj] = (f32x4){0.f, 0.f, 0.f, 0.f};

    auto stage = [&](int kt, int buf) {
        // x: 1 glds per wave; OOB chunks (kt==24, sc>=4) clamped to chunk 0 (zeroed at read)
        int k = kt * 32 + sc * 4;
        const float* xs = xrowp + ((k + 4 <= DIN) ? k : kt * 32);
        __builtin_amdgcn_global_load_lds(
            (const __attribute__((address_space(1))) unsigned*)xs,
            (__attribute__((address_space(3))) unsigned*)(&xl[buf][w * 256]), 16, 0, 0);
        // W: 2 glds per wave; block's tiles = ch*8 + {2w, 2w+1}
        const ushort_t* ws0 = Wb + ((size_t)(kt * NCT + ch * 8 + 2 * w)) * 512 + lane * 8;
        __builtin_amdgcn_global_load_lds(
            (const __attribute__((address_space(1))) unsigned*)ws0,
            (__attribute__((address_space(3))) unsigned*)(&wt[buf][(2 * w) * 512]), 16, 0, 0);
        __builtin_amdgcn_global_load_lds(
            (const __attribute__((address_space(1))) unsigned*)(ws0 + 512),
            (__attribute__((address_space(3))) unsigned*)(&wt[buf][(2 * w + 1) * 512]), 16, 0, 0);
    };

    auto compute = [&](int kt, int buf) {
        const int row_l = rt * 16 + (lane & 15);
        const int j = lane >> 4;
        const int c1 = (2 * j + row_l) & 7, c2 = (2 * j + 1 + row_l) & 7;
        f32x4 xa = *(const f32x4*)(&xl[buf][(row_l * 8 + c1) * 4]);
        f32x4 xb = *(const f32x4*)(&xl[buf][(row_l * 8 + c2) * 4]);
        bool valid = (kt * 32 + j * 8) < DIN;   // frag-aligned K tail
        bf16x8 af;
        unsigned* afp = (unsigned*)&af;
        afp[0] = valid ? pack2(xa[0], xa[1]) : 0u;
        afp[1] = valid ? pack2(xa[2], xa[3]) : 0u;
        afp[2] = valid ? pack2(xb[0], xb[1]) : 0u;
        afp[3] = valid ? pack2(xb[2], xb[3]) : 0u;
#pragma unroll
        for (int jj = 0; jj < 4; ++jj) {
            bf16x8 bf = *(const bf16x8*)(&wt[buf][(g * 4 + jj) * 512 + lane * 8]);
            acc[jj] = __builtin_amdgcn_mfma_f32_16x16x32_bf16(af, bf, acc[jj], 0, 0, 0);
        }
    };

    stage(0, 0);
    __syncthreads();
    for (int kt = 0; kt < KTILES; ++kt) {
        const int cur = kt & 1;
        if (kt + 1 < KTILES) stage(kt + 1, cur ^ 1);
        compute(kt, cur);
        __syncthreads();
    }

    // epilogue: softplus+bias, reduce 16 rows per wave, atomic per column
    const int jcol = lane & 15, rgrp = lane >> 4;
#pragma unroll
    for (int jj = 0; jj < 4; ++jj) {
        int j = (ch * 8 + g * 4 + jj) * 16 + jcol;
        float bias = (j < 100) ? b0[j] : ((j < 200) ? b1[j - 100] : 0.f);
        float v = 0.f;
#pragma unroll
        for (int r = 0; r < 4; ++r) v += softplusf(acc[jj][r] + bias);
        v += __shfl_xor(v, 16);
        v += __shfl_xor(v, 32);
        if (j < 200 && rgrp == 0) atomicAdd(&ws[j], v);
    }
}

// ---- mean/cov, z, Dkl (single block) ----
__global__ __launch_bounds__(256) void middle_kernel(
    const float* __restrict__ eps, float* __restrict__ ws)
{
    __shared__ float red[256];
    const int tid = threadIdx.x;
    float contrib = 0.f;
    if (tid < DZ) {
        const float inv = 1.f / (float)NROWS;
        float mm = ws[tid] * inv;
        float cc = ws[100 + tid] * inv;
        contrib = 0.5f * __logf(cc);
#pragma unroll
        for (int s = 0; s < NS; ++s) {
            float e = eps[s * DZ + tid];
            float zz = mm + cc * e;
            ws[WS_Z + s * DZ + tid] = zz;
            contrib += (0.5f * cc * e * e - 0.5f * zz * zz) * (1.f / NS);
        }
    }
    red[tid] = contrib;
    __syncthreads();
    for (int off = 128; off > 0; off >>= 1) {
        if (tid < off) red[tid] += red[tid + off];
        __syncthreads();
    }
    if (tid == 0) ws[201] = red[0];
}

// ---- y2 = (z @ W2.T + b2) * log2e ----
__global__ __launch_bounds__(256) void y2_kernel(
    const float* __restrict__ W2, const float* __restrict__ b2,
    float* __restrict__ ws)
{
    int wid  = (int)((blockIdx.x * 256 + threadIdx.x) >> 6);
    int lane = threadIdx.x & 63;
    if (wid >= NS * DIN) return;
    int s = wid / DIN, i = wid % DIN;
    const float* zz = ws + WS_Z + s * DZ;
    const float* wr = W2 + (size_t)i * DZ;
    float p = 0.f;
    for (int d = lane; d < DZ; d += 64) p += zz[d] * wr[d];
#pragma unroll
    for (int off = 32; off > 0; off >>= 1) p += __shfl_xor(p, off);
    if (lane == 0) ws[WS_Y2 + wid] = (p + b2[i]) * 1.4426950408889634f;
}

// ---- sum over (b,s) of log(prod_i sigmoid((2x-1)*y) + 1e-3) ----
// Fast path: certified bound. log2 p = -sum log2(1+2^u) <= -sum max(u,0), u=(1-2x)*y2.
// If sum max(u,0) >= 40, then p < 2^-40 < ulp(0.001)/2 -> term == ln(0.001) exactly
// (reference's fp32 prod underflows to 0 likewise). Otherwise: honest transcendental path.
__global__ __launch_bounds__(256) void pv_kernel(
    const float* __restrict__ x, const float* __restrict__ ws, float* __restrict__ out_sum)
{
    __shared__ float y2s[NS * DIN];
    __shared__ float bsum;
    const int tid = threadIdx.x;
    for (int i = tid; i < NS * DIN / 4; i += 256)
        ((float4*)y2s)[i] = ((const float4*)(ws + WS_Y2))[i];
    if (tid == 0) bsum = 0.f;
    __syncthreads();

    const int lane = tid & 63;
    const int wid  = (int)((blockIdx.x * 256 + tid) >> 6);
    const int nw   = gridDim.x * 4;
    const float L001 = -6.90775527898f;   // ln(0.001)
    float wacc = 0.f;

    for (int b = wid; b < NROWS; b += nw) {
        const float4* xr = (const float4*)(x + (size_t)b * DIN);
        float bnd[NS];
#pragma unroll
        for (int s = 0; s < NS; ++s) bnd[s] = 0.f;
#pragma unroll
        for (int m = 0; m < 4; ++m) {
            int i4 = lane + m * 64;
            if (i4 < DIN / 4) {
                float4 xv = xr[i4];
                float n0 = 1.f - 2.f * xv.x;
                float n1 = 1.f - 2.f * xv.y;
                float n2 = 1.f - 2.f * xv.z;
                float n3 = 1.f - 2.f * xv.w;
#pragma unroll
                for (int s = 0; s < NS; ++s) {
                    const float4 yv = *(const float4*)(y2s + s * DIN + i4 * 4);
                    bnd[s] += fmaxf(n0 * yv.x, 0.f) + fmaxf(n1 * yv.y, 0.f)
                            + fmaxf(n2 * yv.z, 0.f) + fmaxf(n3 * yv.w, 0.f);
                }
            }
        }
#pragma unroll
        for (int s = 0; s < NS; ++s) {
#pragma unroll
            for (int off = 32; off > 0; off >>= 1) bnd[s] += __shfl_xor(bnd[s], off);
        }
        bool anyslow = false;
#pragma unroll
        for (int s = 0; s < NS; ++s) anyslow = anyslow || !(bnd[s] >= 40.f);
        float rs;
        if (!anyslow) {
            rs = 10.f * L001;
        } else {
            rs = 0.f;
#pragma unroll
            for (int s = 0; s < NS; ++s) {
                if (bnd[s] >= 40.f) { rs += L001; continue; }
                float a = 0.f;
#pragma unroll
                for (int m = 0; m < 4; ++m) {
                    int i4 = lane + m * 64;
                    if (i4 < DIN / 4) {
                        float4 xv = xr[i4];
                        float n0 = 1.f - 2.f * xv.x;
                        float n1 = 1.f - 2.f * xv.y;
                        float n2 = 1.f - 2.f * xv.z;
                        float n3 = 1.f - 2.f * xv.w;
                        const float4 yv = *(const float4*)(y2s + s * DIN + i4 * 4);
                        a -= __builtin_amdgcn_logf(1.f + __builtin_amdgcn_exp2f(n0 * yv.x));
                        a -= __builtin_amdgcn_logf(1.f + __builtin_amdgcn_exp2f(n1 * yv.y));
                        a -= __builtin_amdgcn_logf(1.f + __builtin_amdgcn_exp2f(n2 * yv.z));
                        a -= __builtin_amdgcn_logf(1.f + __builtin_amdgcn_exp2f(n3 * yv.w));
                    }
                }
#pragma unroll
                for (int off = 32; off > 0; off >>= 1) a += __shfl_xor(a, off);
                rs += __logf(__builtin_amdgcn_exp2f(a) + 0.001f);
            }
        }
        wacc += rs;
    }
    if (lane == 0) atomicAdd(&bsum, wacc);
    __syncthreads();
    if (tid == 0) atomicAdd(out_sum, bsum);
}

// ---- final scalar ----
__global__ void final_kernel(const float* __restrict__ ws, float* __restrict__ out)
{
    float E = ws[200] * (1.f / ((float)NROWS * (float)NS));
    out[0] = -(E + ws[201]);
}

extern "C" void kernel_launch(void* const* d_in, const int* in_sizes, int n_in,
                              void* d_out, int out_size, void* d_ws, size_t ws_size,
                              hipStream_t stream)
{
    const float* x   = (const float*)d_in[0];
    const float* W0  = (const float*)d_in[1];
    const float* b0  = (const float*)d_in[2];
    const float* W1  = (const float*)d_in[3];
    const float* b1  = (const float*)d_in[4];
    const float* W2  = (const float*)d_in[5];
    const float* b2  = (const float*)d_in[6];
    const float* eps = (const float*)d_in[7];
    float* out = (float*)d_out;
    float* ws  = (float*)d_ws;
    ushort_t* Wb = (ushort_t*)(ws + WS_WB);

    hipMemsetAsync(ws, 0, 256 * sizeof(float), stream);
    wb2_kernel<<<(KTILES * NCT * 64 + 255) / 256, 256, 0, stream>>>(W0, W1, Wb);
    colmean_mfma<<<STRIPS * 2, 256, 0, stream>>>(x, Wb, b0, b1, ws);
    middle_kernel<<<1, 256, 0, stream>>>(eps, ws);
    y2_kernel<<<(NS * DIN * 64) / 256, 256, 0, stream>>>(W2, b2, ws);
    pv_kernel<<<1024, 256, 0, stream>>>(x, ws, ws + 200);
    final_kernel<<<1, 1, 0, stream>>>(ws, out);
}

// Round 5
// 71.010 us; speedup vs baseline: 7.4387x; 1.4566x over previous
//
#include <hip/hip_runtime.h>
#include <hip/hip_bf16.h>
#include <math.h>

#define NROWS 16384
#define DIN   784
#define DZ    100
#define NS    10
#define NCT   16           // 16 col-tiles x 16 = 256 cols (200 real + 56 zero pad)
#define KTILES 25          // 25 * 32 = 800 >= 784, tail frags zeroed
#define BM    64
#define BND_THR 45.0f

typedef unsigned short ushort_t;
typedef short bf16x8 __attribute__((ext_vector_type(8)));
typedef float f32x4  __attribute__((ext_vector_type(4)));

// ws layout (float offsets):
//  [0..199]   colsum softplus (atomic)   [200] pv log-sum (atomic)   [201] Dkl
//  [208..8047] y2[s][i] = y * log2e      [8064..9063] z[s][d]
//  [16384..]   Wb2: bf16 fragment-swizzled W, 25*16*512 ushorts (400 KB)
#define WS_Y2 208
#define WS_Z  8064
#define WS_WB 16384

__device__ __forceinline__ float softplusf(float v) {
    return fmaxf(v, 0.f) + log1pf(__expf(-fabsf(v)));
}
__device__ __forceinline__ unsigned pack2(float lo, float hi) {
    float2 f2; f2.x = lo; f2.y = hi;
    __hip_bfloat162 h2 = __float22bfloat162_rn(f2);
    return *reinterpret_cast<unsigned*>(&h2);
}

// ---- W -> bf16, pre-swizzled to MFMA B-fragment order ----
// Wb[((kt*16 + ct)*64 + l)*8 + j] = W[ct*16 + (l&15)][kt*32 + (l>>4)*8 + j]
__global__ __launch_bounds__(256) void wb2_kernel(
    const float* __restrict__ W0, const float* __restrict__ W1, ushort_t* __restrict__ Wb)
{
    int t = blockIdx.x * 256 + threadIdx.x;
    if (t >= KTILES * NCT * 64) return;
    int kt = t >> 10;
    int r  = t & 1023;
    int ct = r >> 6, l = r & 63;
    int col = ct * 16 + (l & 15);
    int k0  = kt * 32 + (l >> 4) * 8;
    uint4 o = make_uint4(0u, 0u, 0u, 0u);
    if (col < 200 && k0 < DIN) {           // frag-aligned tail: k0=784,792 zeroed
        const float* src = (col < 100 ? W0 + (size_t)col * DIN
                                      : W1 + (size_t)(col - 100) * DIN) + k0;
        float4 a = *(const float4*)src;
        float4 b = *(const float4*)(src + 4);
        o.x = pack2(a.x, a.y); o.y = pack2(a.z, a.w);
        o.z = pack2(b.x, b.y); o.w = pack2(b.z, b.w);
    }
    *(uint4*)(Wb + (size_t)t * 8) = o;
}

// ---- MFMA column-sum of softplus(x@W.T + b) ----
// 256 blocks x 512 thr (8 waves). NO LDS staging, NO barriers in the K-loop:
// each wave loads its A-frag (x rows, fp32->bf16 inline) and 8 B-frags (Wb,
// coalesced 1KB, L2-resident) straight to registers, 2-deep named reg dbuf.
__global__ __launch_bounds__(512, 2) void colmean_mfma(
    const float* __restrict__ x, const ushort_t* __restrict__ Wb,
    const float* __restrict__ b0, const float* __restrict__ b1,
    float* __restrict__ ws)
{
    __shared__ float colsum[256];
    const int tid = threadIdx.x;
    const int lane = tid & 63, w = tid >> 6;
    const int rg = w >> 1, h = w & 1;          // row-group 0..3, col-half 0..1
    const int row = blockIdx.x * BM + rg * 16 + (lane & 15);
    const int kc = lane >> 4;
    const int tilebase = h * 8;
    const float* xp = x + (size_t)row * DIN;

    f32x4 acc[8];
#pragma unroll
    for (int jj = 0; jj < 8; ++jj) acc[jj] = (f32x4){0.f, 0.f, 0.f, 0.f};

    float4 a0A, a1A, a0B, a1B;
    uint4 bA[8], bB[8];

    auto loadA = [&](int kt, float4& a0, float4& a1) {
        int k0 = kt * 32 + kc * 8;
        if (k0 + 8 > DIN) k0 = 768;            // junk ok: W frags are zero at k>=784
        a0 = *(const float4*)(xp + k0);
        a1 = *(const float4*)(xp + k0 + 4);
    };
    auto loadB = [&](int kt, uint4* bb) {
#pragma unroll
        for (int jj = 0; jj < 8; ++jj)
            bb[jj] = *(const uint4*)(Wb + ((size_t)(kt * NCT + tilebase + jj) * 64 + lane) * 8);
    };
    auto comp = [&](const float4& a0, const float4& a1, const uint4* bb) {
        bf16x8 af; unsigned* afp = (unsigned*)&af;
        afp[0] = pack2(a0.x, a0.y); afp[1] = pack2(a0.z, a0.w);
        afp[2] = pack2(a1.x, a1.y); afp[3] = pack2(a1.z, a1.w);
#pragma unroll
        for (int jj = 0; jj < 8; ++jj)
            acc[jj] = __builtin_amdgcn_mfma_f32_16x16x32_bf16(
                af, *(const bf16x8*)&bb[jj], acc[jj], 0, 0, 0);
    };

    loadA(0, a0A, a1A); loadB(0, bA);
    for (int i = 0; i < 12; ++i) {             // covers kt = 0..23, loads up to 24
        loadA(2 * i + 1, a0B, a1B); loadB(2 * i + 1, bB);
        comp(a0A, a1A, bA);
        loadA(2 * i + 2, a0A, a1A); loadB(2 * i + 2, bA);
        comp(a0B, a1B, bB);
    }
    comp(a0A, a1A, bA);                        // kt = 24

    // epilogue: softplus+bias, per-wave 16-row reduce, LDS combine, 1 atomic/col/block
    for (int i2 = tid; i2 < 256; i2 += 512) colsum[i2] = 0.f;
    __syncthreads();
    const int jcol = lane & 15, rgrp = lane >> 4;
#pragma unroll
    for (int jj = 0; jj < 8; ++jj) {
        int j = (tilebase + jj) * 16 + jcol;
        float bias = (j < 100) ? b0[j] : ((j < 200) ? b1[j - 100] : 0.f);
        float v = 0.f;
#pragma unroll
        for (int r = 0; r < 4; ++r) v += softplusf(acc[jj][r] + bias);
        v += __shfl_xor(v, 16);
        v += __shfl_xor(v, 32);
        if (rgrp == 0 && j < 200) atomicAdd(&colsum[j], v);
    }
    __syncthreads();
    if (tid < 200) atomicAdd(&ws[tid], colsum[tid]);
}

// ---- mean/cov, z, Dkl (single block) ----
__global__ __launch_bounds__(256) void middle_kernel(
    const float* __restrict__ eps, float* __restrict__ ws)
{
    __shared__ float red[256];
    const int tid = threadIdx.x;
    float contrib = 0.f;
    if (tid < DZ) {
        const float inv = 1.f / (float)NROWS;
        float mm = ws[tid] * inv;
        float cc = ws[100 + tid] * inv;
        contrib = 0.5f * __logf(cc);
#pragma unroll
        for (int s = 0; s < NS; ++s) {
            float e = eps[s * DZ + tid];
            float zz = mm + cc * e;
            ws[WS_Z + s * DZ + tid] = zz;
            contrib += (0.5f * cc * e * e - 0.5f * zz * zz) * (1.f / NS);
        }
    }
    red[tid] = contrib;
    __syncthreads();
    for (int off = 128; off > 0; off >>= 1) {
        if (tid < off) red[tid] += red[tid + off];
        __syncthreads();
    }
    if (tid == 0) ws[201] = red[0];
}

// ---- y2 = (z @ W2.T + b2) * log2e ----
__global__ __launch_bounds__(256) void y2_kernel(
    const float* __restrict__ W2, const float* __restrict__ b2,
    float* __restrict__ ws)
{
    int wid  = (int)((blockIdx.x * 256 + threadIdx.x) >> 6);
    int lane = threadIdx.x & 63;
    if (wid >= NS * DIN) return;
    int s = wid / DIN, i = wid % DIN;
    const float* zz = ws + WS_Z + s * DZ;
    const float* wr = W2 + (size_t)i * DZ;
    float p = 0.f;
    for (int d = lane; d < DZ; d += 64) p += zz[d] * wr[d];
#pragma unroll
    for (int off = 32; off > 0; off >>= 1) p += __shfl_xor(p, off);
    if (lane == 0) ws[WS_Y2 + wid] = (p + b2[i]) * 1.4426950408889634f;
}

// ---- sum over (b,s) of log(prod_i sigmoid((2x-1)*y) + 1e-3) ----
// MFMA-certified bound: sum_i max(u,0) = 0.5*(n.y + |n|.|y|) (bit-exact identity),
// u = (1-2x)*y2. bnd >= 45 (minus bf16 slack) => p < 2^-43 << ulp(0.001)/2 =>
// term == ln(0.001) exactly (ref fp32 prod underflows). Honest fallback otherwise.
__global__ __launch_bounds__(256) void pv_kernel(
    const float* __restrict__ x, const float* __restrict__ ws, float* __restrict__ out_sum)
{
    __shared__ ushort_t yf[KTILES * 512];   // y2 B-frags (bf16)
    __shared__ ushort_t ya[KTILES * 512];   // |y2| B-frags
    __shared__ float bsum;
    const int tid = threadIdx.x;
    const int lane = tid & 63, w = tid >> 6;

    for (int idx = tid; idx < KTILES * 64; idx += 256) {
        int kt = idx >> 6, l = idx & 63;
        int ss = l & 15, k0 = kt * 32 + (l >> 4) * 8;
        uint4 o = make_uint4(0u, 0u, 0u, 0u), oa = o;
        if (ss < NS && k0 < DIN) {
            const float* src = ws + WS_Y2 + ss * DIN + k0;
            float4 a = *(const float4*)src, b = *(const float4*)(src + 4);
            o.x = pack2(a.x, a.y); o.y = pack2(a.z, a.w);
            o.z = pack2(b.x, b.y); o.w = pack2(b.z, b.w);
            oa.x = o.x & 0x7FFF7FFFu; oa.y = o.y & 0x7FFF7FFFu;
            oa.z = o.z & 0x7FFF7FFFu; oa.w = o.w & 0x7FFF7FFFu;
        }
        *(uint4*)(yf + (size_t)idx * 8) = o;
        *(uint4*)(ya + (size_t)idx * 8) = oa;
    }
    if (tid == 0) bsum = 0.f;
    __syncthreads();

    const int tile = blockIdx.x * 4 + w;       // 1024 tiles of 16 rows
    const int row  = tile * 16 + (lane & 15);
    const int kc   = lane >> 4;
    const int s    = lane & 15;
    const float* xp = x + (size_t)row * DIN;
    const float L001 = -6.90775527898f;        // ln(0.001f)

    f32x4 acc0 = (f32x4){0.f, 0.f, 0.f, 0.f};
    f32x4 acc1 = (f32x4){0.f, 0.f, 0.f, 0.f};
    float4 a0A, a1A, a0B, a1B;

    auto loadA = [&](int kt, float4& a0, float4& a1) {
        int k0 = kt * 32 + kc * 8;
        if (k0 + 8 > DIN) k0 = 768;            // junk ok: y frags zero at k>=784
        a0 = *(const float4*)(xp + k0);
        a1 = *(const float4*)(xp + k0 + 4);
    };
    auto comp = [&](int kt, const float4& a0, const float4& a1) {
        bf16x8 nf; unsigned* p = (unsigned*)&nf;
        p[0] = pack2(1.f - 2.f * a0.x, 1.f - 2.f * a0.y);
        p[1] = pack2(1.f - 2.f * a0.z, 1.f - 2.f * a0.w);
        p[2] = pack2(1.f - 2.f * a1.x, 1.f - 2.f * a1.y);
        p[3] = pack2(1.f - 2.f * a1.z, 1.f - 2.f * a1.w);
        bf16x8 na; unsigned* q = (unsigned*)&na;
        q[0] = p[0] & 0x7FFF7FFFu; q[1] = p[1] & 0x7FFF7FFFu;
        q[2] = p[2] & 0x7FFF7FFFu; q[3] = p[3] & 0x7FFF7FFFu;
        bf16x8 fy = *(const bf16x8*)(yf + (size_t)kt * 512 + lane * 8);
        bf16x8 fa = *(const bf16x8*)(ya + (size_t)kt * 512 + lane * 8);
        acc0 = __builtin_amdgcn_mfma_f32_16x16x32_bf16(nf, fy, acc0, 0, 0, 0);
        acc1 = __builtin_amdgcn_mfma_f32_16x16x32_bf16(na, fa, acc1, 0, 0, 0);
    };

    loadA(0, a0A, a1A);
    for (int i = 0; i < 12; ++i) {
        loadA(2 * i + 1, a0B, a1B);
        comp(2 * i, a0A, a1A);
        loadA(2 * i + 2, a0A, a1A);
        comp(2 * i + 1, a0B, a1B);
    }
    comp(24, a0A, a1A);

    float bnd[4];
#pragma unroll
    for (int r = 0; r < 4; ++r) bnd[r] = 0.5f * (acc0[r] + acc1[r]);

    float wsum;
    bool lslow = (s < NS) &&
        (fminf(fminf(bnd[0], bnd[1]), fminf(bnd[2], bnd[3])) < BND_THR);
    unsigned long long m = __ballot(lslow);
    if (m == 0ull) {
        wsum = 160.f * L001;                   // 16 rows x 10 samples, all certified
    } else {
        int nslow = 0;
        float slowsum = 0.f;
#pragma unroll
        for (int r = 0; r < 4; ++r) {
            unsigned long long mr = __ballot((s < NS) && (bnd[r] < BND_THR));
            nslow += (int)__popcll(mr);
            while (mr) {
                int src = (int)__ffsll(mr) - 1; mr &= (mr - 1);
                int ss = src & 15;
                int rrow = tile * 16 + (src >> 4) * 4 + r;
                const float* xq = x + (size_t)rrow * DIN;
                const float* yq = ws + WS_Y2 + ss * DIN;
                float a = 0.f;
                for (int i = lane; i < DIN; i += 64)
                    a -= __builtin_amdgcn_logf(
                        1.f + __builtin_amdgcn_exp2f((1.f - 2.f * xq[i]) * yq[i]));
#pragma unroll
                for (int off = 32; off > 0; off >>= 1) a += __shfl_xor(a, off);
                slowsum += __logf(__builtin_amdgcn_exp2f(a) + 0.001f);
            }
        }
        wsum = (float)(160 - nslow) * L001 + slowsum;
    }
    if (lane == 0) atomicAdd(&bsum, wsum);
    __syncthreads();
    if (tid == 0) atomicAdd(out_sum, bsum);
}

// ---- final scalar ----
__global__ void final_kernel(const float* __restrict__ ws, float* __restrict__ out)
{
    float E = ws[200] * (1.f / ((float)NROWS * (float)NS));
    out[0] = -(E + ws[201]);
}

extern "C" void kernel_launch(void* const* d_in, const int* in_sizes, int n_in,
                              void* d_out, int out_size, void* d_ws, size_t ws_size,
                              hipStream_t stream)
{
    const float* x   = (const float*)d_in[0];
    const float* W0  = (const float*)d_in[1];
    const float* b0  = (const float*)d_in[2];
    const float* W1  = (const float*)d_in[3];
    const float* b1  = (const float*)d_in[4];
    const float* W2  = (const float*)d_in[5];
    const float* b2  = (const float*)d_in[6];
    const float* eps = (const float*)d_in[7];
    float* out = (float*)d_out;
    float* ws  = (float*)d_ws;
    ushort_t* Wb = (ushort_t*)(ws + WS_WB);

    hipMemsetAsync(ws, 0, 256 * sizeof(float), stream);
    wb2_kernel<<<(KTILES * NCT * 64 + 255) / 256, 256, 0, stream>>>(W0, W1, Wb);
    colmean_mfma<<<NROWS / BM, 512, 0, stream>>>(x, Wb, b0, b1, ws);
    middle_kernel<<<1, 256, 0, stream>>>(eps, ws);
    y2_kernel<<<(NS * DIN * 64) / 256, 256, 0, stream>>>(W2, b2, ws);
    pv_kernel<<<NROWS / BM, 256, 0, stream>>>(x, ws, ws + 200);
    final_kernel<<<1, 1, 0, stream>>>(ws, out);
}